// Round 23
// baseline (316.810 us; speedup 1.0000x reference)
//
#include <hip/hip_runtime.h>
#include <hip/hip_bf16.h>
#include <stdint.h>

// MultiheadAttention (T=512, B=32, H=16, hd=64, D=1024); bmm batched over seq dim.
// R22 base (best: 315.4us) + one attributable change: gemm_bb (256,4).
// Occupancy ladder validated: 2 blk (MfmaUtil 27, 158us) -> 3 blk (35, 125us);
// footprint 60 VGPR + 64 acc-AGPR = 124 <= 128 cap at 4 waves/EU; LDS 4x32=128KB.

typedef __attribute__((ext_vector_type(8))) short bf16x8;
typedef __attribute__((ext_vector_type(4))) float f32x4;
typedef unsigned short u16;
typedef unsigned int u32;

typedef __attribute__((address_space(1))) const unsigned int as1_u32;
typedef __attribute__((address_space(3))) unsigned int as3_u32;

#define KSC 0.18033688011112042f   // log2(e)/sqrt(64)

__device__ __forceinline__ void glds16(const void* g, void* l) {
    __builtin_amdgcn_global_load_lds((as1_u32*)g, (as3_u32*)l, 16, 0, 0);
}

__device__ __forceinline__ u16 f2bf(float f) {
    u32 u = __builtin_bit_cast(u32, f);
    u32 r = (u + 0x7FFFu + ((u >> 16) & 1u)) >> 16;
    return (u16)r;
}

// HW packed fp32->bf16 RNE: lo(bf16 of a) | hi(bf16 of b). One VALU inst.
__device__ __forceinline__ u32 cvtpk(float a, float b) {
    u32 r;
    asm("v_cvt_pk_bf16_f32 %0, %1, %2" : "=v"(r) : "v"(a), "v"(b));
    return r;
}

// 16-lane-group allreduce, fused DPP adds (src0 routed through DPP network).
__device__ __forceinline__ float red16(float v) {
    float t;
    asm("v_add_f32_dpp %0, %1, %1 quad_perm:[1,0,3,2] row_mask:0xf bank_mask:0xf"
        : "=v"(t) : "v"(v));
    asm("v_add_f32_dpp %0, %1, %1 quad_perm:[2,3,0,1] row_mask:0xf bank_mask:0xf"
        : "=v"(v) : "v"(t));
    asm("v_add_f32_dpp %0, %1, %1 row_half_mirror row_mask:0xf bank_mask:0xf"
        : "=v"(t) : "v"(v));
    asm("v_add_f32_dpp %0, %1, %1 row_mirror row_mask:0xf bank_mask:0xf"
        : "=v"(v) : "v"(t));
    return v;
}

// ---------------- query (remap) + key + value + weights fp32 -> bf16 ----
// Wq is pre-scaled by KSC (bias scaled at gemm epilogue).
__global__ void convw_kernel(const float4* __restrict__ query,
                             const float4* __restrict__ key,
                             const float4* __restrict__ value,
                             const float4* __restrict__ Wq, const float4* __restrict__ Wk,
                             const float4* __restrict__ Wv, const float4* __restrict__ Wo,
                             uint2* __restrict__ qx, uint2* __restrict__ kx,
                             uint2* __restrict__ vx,
                             uint2* __restrict__ wqb, uint2* __restrict__ wkb,
                             uint2* __restrict__ wvb, uint2* __restrict__ wob) {
    const int NT = gridDim.x * blockDim.x;
    for (int i = blockIdx.x * blockDim.x + threadIdx.x; i < 13631488; i += NT) {
        float4 v; uint2* d; int di;
        if (i < 4194304) {
            int m = i >> 8, c4 = i & 255;          // qx row m = t*32 + b
            int t = m >> 5, b = m & 31;
            v = query[(b * 512 + t) * 256 + c4];
            d = qx; di = i;
        } else if (i < 8388608) {
            di = i - 4194304; v = key[di]; d = kx;
        } else if (i < 12582912) {
            di = i - 8388608; v = value[di]; d = vx;
        } else {
            int jj = i - 12582912;
            int wsel = jj >> 18; di = jj & 262143;
            const float4* s = wsel == 0 ? Wq : wsel == 1 ? Wk : wsel == 2 ? Wv : Wo;
            d = wsel == 0 ? wqb : wsel == 1 ? wkb : wsel == 2 ? wvb : wob;
            v = s[di];
            if (wsel == 0) { v.x *= KSC; v.y *= KSC; v.z *= KSC; v.w *= KSC; }
        }
        uint2 r;
        r.x = (u32)f2bf(v.x) | ((u32)f2bf(v.y) << 16);
        r.y = (u32)f2bf(v.z) | ((u32)f2bf(v.w) << 16);
        d[di] = r;
    }
}

// ---------------------------------------------------------- bf16 GEMM ----
// Single-buffered m97 structure: {glds(kt); bar; 32 MFMA; bar}. 32KB LDS,
// (256,4): 4 resident blocks/CU (124 regs unified < 128 cap; LDS 128/160KB).
template <int F32OUT>
__global__ __launch_bounds__(256, 4)
void gemm_bb(const u16* __restrict__ A0, const u16* __restrict__ A1,
             const u16* __restrict__ A2,
             const u16* __restrict__ B0, const u16* __restrict__ B1,
             const u16* __restrict__ B2,
             const float* __restrict__ b0, const float* __restrict__ b1,
             const float* __restrict__ b2,
             float s0, float s1, float s2,
             void* __restrict__ C0, void* __restrict__ C1, void* __restrict__ C2) {
    __shared__ __align__(16) u16 As[8192];
    __shared__ __align__(16) u16 Bs[8192];
    const int z = blockIdx.z;
    const u16* A = z == 0 ? A0 : z == 1 ? A1 : A2;
    const u16* B = z == 0 ? B0 : z == 1 ? B1 : B2;
    const float* bias = z == 0 ? b0 : z == 1 ? b1 : b2;
    const float bsc = z == 0 ? s0 : z == 1 ? s1 : s2;
    void* Cp = z == 0 ? C0 : z == 1 ? C1 : C2;
    const int tid = threadIdx.x;
    const int id = blockIdx.x;
    const int xcd = id & 7, j = id >> 3;
    const int ny = j & 7, band = xcd * 16 + (j >> 3);
    const long N0 = (long)ny * 128;
    const long M0 = (long)band * 128;
    const int lane = tid & 63, wv = tid >> 6;
    const int l15 = lane & 15, g = lane >> 4;
    const int wm = (wv >> 1) * 64, wn = (wv & 1) * 64;

    auto gldsAB = [&](int kt) {
#pragma unroll
        for (int i2 = 0; i2 < 4; ++i2) {
            int q = tid + 256 * i2; int r = q >> 3, c16 = q & 7;
            int c16s = c16 ^ (r & 7);   // pre-swizzled source: lds stays linear
            char* lbA = (char*)As + (i2 * 256 + wv * 64) * 16;
            char* lbB = (char*)Bs + (i2 * 256 + wv * 64) * 16;
            glds16(A + (M0 + r) * 1024 + kt * 64 + c16s * 8, lbA);
            glds16(B + (N0 + r) * 1024 + kt * 64 + c16s * 8, lbB);
        }
    };
    f32x4 acc[4][4] = {};
    const int swz = (l15 & 7) << 4;
    for (int kt = 0; kt < 16; ++kt) {
        gldsAB(kt);
        __syncthreads();   // glds drained: tile kt resident
#pragma unroll
        for (int kk = 0; kk < 2; ++kk) {
            bf16x8 av[4], bvv[4];
#pragma unroll
            for (int mt = 0; mt < 4; ++mt) {
                int row = wm + mt * 16 + l15;
                av[mt] = *(const bf16x8*)((const char*)As + row * 128 + ((kk * 64 + g * 16) ^ swz));
            }
#pragma unroll
            for (int nt = 0; nt < 4; ++nt) {
                int row = wn + nt * 16 + l15;
                bvv[nt] = *(const bf16x8*)((const char*)Bs + row * 128 + ((kk * 64 + g * 16) ^ swz));
            }
#pragma unroll
            for (int mt = 0; mt < 4; ++mt)
#pragma unroll
                for (int nt = 0; nt < 4; ++nt)
                    acc[mt][nt] = __builtin_amdgcn_mfma_f32_16x16x32_bf16(av[mt], bvv[nt], acc[mt][nt], 0, 0, 0);
        }
        __syncthreads();   // all reads done before next tile's glds
    }
    float bsv[4];
#pragma unroll
    for (int nt = 0; nt < 4; ++nt) bsv[nt] = bias[N0 + wn + nt * 16 + l15] * bsc;
#pragma unroll
    for (int mt = 0; mt < 4; ++mt)
#pragma unroll
        for (int nt = 0; nt < 4; ++nt)
#pragma unroll
            for (int r = 0; r < 4; ++r) {
                long m = M0 + wm + mt * 16 + g * 4 + r;
                long n = N0 + wn + nt * 16 + l15;
                float v = acc[mt][nt][r] + bsv[nt];
                if (F32OUT) ((float*)Cp)[m * 1024 + n] = v;
                else        ((u16*)Cp)[m * 1024 + n] = f2bf(v);
            }
}

// ------------------------------------------------- V transpose: [t][c][e] -> [t][e][c]
__global__ __launch_bounds__(256)
void vtrans_kernel(const u16* __restrict__ v_ws, u16* __restrict__ vt) {
    __shared__ __align__(16) u16 tl[64][136];
    const int bid = blockIdx.x;
    const int t = bid >> 2, c0 = (bid & 3) * 128;
    const u16* src = v_ws + (size_t)t * 32768 + (size_t)c0 * 64;
#pragma unroll
    for (int i = 0; i < 4; ++i) {
        int ch = i * 256 + threadIdx.x;
        int rc = ch >> 3, e0 = (ch & 7) * 8;
        bf16x8 v8 = *(const bf16x8*)(src + rc * 64 + e0);
#pragma unroll
        for (int j = 0; j < 8; ++j) tl[e0 + j][rc] = (u16)v8[j];
    }
    __syncthreads();
    u16* dst = vt + (size_t)t * 32768 + c0;
#pragma unroll
    for (int i = 0; i < 4; ++i) {
        int ch = i * 256 + threadIdx.x;
        int e = ch >> 4, cc = (ch & 15) * 8;
        *(bf16x8*)(dst + (size_t)e * 512 + cc) = *(const bf16x8*)(&tl[e][cc]);
    }
}

// ------------------------------------------------------------- fused attn ----
// Grid 2048: block = (t, it); 8 waves; wave owns bb = it*8+wv; cols c = 32*l15+bb.
// 3 barriers: {stage all K; BAR; all QK^T+exp2+cvt_pk; BAR; stage all V^T +
// w-phase (fused-DPP reduce); BAR; all PV; epilogue}. Q pre-scaled by KSC.
__global__ __launch_bounds__(512, 2)
void attn_kernel(const u16* __restrict__ Q, const u16* __restrict__ K,
                 const u16* __restrict__ VT, u16* __restrict__ ctx,
                 float* __restrict__ wout) {
    __shared__ __align__(16) char smem[65536];
    const int bid = blockIdx.x;
    const int wk_ = (bid & 7) * 256 + (bid >> 3);   // bijective (2048 % 8 == 0)
    const int t = wk_ >> 2, it = wk_ & 3;
    const int tid = threadIdx.x, lane = tid & 63, wv = tid >> 6;
    const int l15 = lane & 15, g = lane >> 4;
    const int swk = (l15 & 7) << 4;
    const int bb = it * 8 + wv;

    const u16* Kt = K + (size_t)t * 32768;
    const u16* Vtt = VT + (size_t)t * 32768;   // [e][c] rows of 512

    // ---- stage ALL of K (64KB): [512 s][128B], 16B-chunk swizzle c16^(sl&7) ----
    {
#pragma unroll
        for (int hh = 0; hh < 8; ++hh) {
            int idx = hh * 512 + tid;
            int sl = idx >> 3, c16 = idx & 7;
            int csw = c16 ^ (sl & 7);
            glds16(Kt + (size_t)sl * 64 + csw * 8, smem + hh * 8192 + wv * 1024);
        }
    }
    const int c = 32 * l15 + bb;
    const u16* qrow = Q + ((size_t)t * 512 + c) * 64;
    bf16x8 qb0 = *(const bf16x8*)(qrow + g * 8);
    bf16x8 qb1 = *(const bf16x8*)(qrow + 32 + g * 8);
    __syncthreads();   // BAR 1: K resident

    // ---- all QK^T + exp2 + cvt_pk, barrier-free (Q pre-scaled: no ksc mul) ----
    float sum = 0.f;
    bf16x8 pP[16];
    __builtin_amdgcn_s_setprio(1);
#pragma unroll
    for (int mq = 0; mq < 16; ++mq) {
        union { bf16x8 v; u32 u[4]; } pa;
#pragma unroll
        for (int h2 = 0; h2 < 2; ++h2) {
            int lsl = 2 * mq + h2;   // 0..31, s = lsl*16 + 4g + r
            const char* rowp = smem + (lsl * 16 + l15) * 128;
            bf16x8 a0 = *(const bf16x8*)(rowp + ((g * 16) ^ swk));
            bf16x8 a1 = *(const bf16x8*)(rowp + ((64 + g * 16) ^ swk));
            f32x4 zz = {0.f, 0.f, 0.f, 0.f};
            zz = __builtin_amdgcn_mfma_f32_16x16x32_bf16(a0, qb0, zz, 0, 0, 0);
            zz = __builtin_amdgcn_mfma_f32_16x16x32_bf16(a1, qb1, zz, 0, 0, 0);
            float e0 = exp2f(zz[0]), e1 = exp2f(zz[1]);
            float e2 = exp2f(zz[2]), e3 = exp2f(zz[3]);
            sum += (e0 + e1) + (e2 + e3);
            pa.u[2 * h2]     = cvtpk(e0, e1);
            pa.u[2 * h2 + 1] = cvtpk(e2, e3);
        }
        pP[mq] = pa.v;
    }
    __builtin_amdgcn_s_setprio(0);
    sum += __shfl_xor(sum, 16);
    sum += __shfl_xor(sum, 32);
    const float inv = 1.f / sum;
    __syncthreads();   // BAR 2: all waves done reading K

    // ---- stage ALL of V^T (64KB, overwrites K): rows e = 1024B, chunk c6^(e&7) ----
    {
#pragma unroll
        for (int hh = 0; hh < 8; ++hh) {
            int ch = hh * 512 + tid;
            int e = ch >> 6, c6 = ch & 63;
            int csw = c6 ^ (e & 7);
            glds16(Vtt + (size_t)e * 512 + csw * 8, smem + hh * 8192 + wv * 1024);
        }
    }
    // ---- w head-mean (fused-DPP allreduce over l15) — V transfer underneath ----
    {
        const float inv16 = inv * 0.0625f;
        float4 wreg0 = {0.f, 0.f, 0.f, 0.f}, wreg1 = {0.f, 0.f, 0.f, 0.f};
#pragma unroll
        for (int st = 0; st < 32; ++st) {
            union { bf16x8 v; u32 u[4]; } pu; pu.v = pP[st >> 1];
            u32 ua = pu.u[(st & 1) * 2], ub = pu.u[(st & 1) * 2 + 1];
            float v0 = __builtin_bit_cast(float, ua << 16) * inv16;
            float v1 = __builtin_bit_cast(float, ua & 0xFFFF0000u) * inv16;
            float v2 = __builtin_bit_cast(float, ub << 16) * inv16;
            float v3 = __builtin_bit_cast(float, ub & 0xFFFF0000u) * inv16;
            v0 = red16(v0); v1 = red16(v1); v2 = red16(v2); v3 = red16(v3);
            if ((st >> 1) == l15) {
                if (st & 1) wreg1 = (float4){v0, v1, v2, v3};
                else        wreg0 = (float4){v0, v1, v2, v3};
            }
        }
        float* wrow = wout + ((size_t)(bb * 512 + t)) * 512 + 32 * l15 + 4 * g;
        *(float4*)(wrow) = wreg0;
        *(float4*)(wrow + 16) = wreg1;
    }
    __syncthreads();   // BAR 3: V^T resident

    // ---- all PV, barrier-free ----
    f32x4 pv[4];
#pragma unroll
    for (int nt = 0; nt < 4; ++nt) pv[nt] = (f32x4){0.f, 0.f, 0.f, 0.f};
    __builtin_amdgcn_s_setprio(1);
#pragma unroll
    for (int mq = 0; mq < 16; ++mq) {
        bf16x8 pa = pP[mq];
#pragma unroll
        for (int nt = 0; nt < 4; ++nt) {
            int e = nt * 16 + l15;
            const char* vrow = smem + e * 1024;
            int off = mq * 64 + 8 * g;
            union { bf16x8 v; uint2 uu[2]; } bv;
            bv.uu[0] = *(const uint2*)(vrow + (off ^ swk));
            bv.uu[1] = *(const uint2*)(vrow + ((off + 32) ^ swk));
            pv[nt] = __builtin_amdgcn_mfma_f32_16x16x32_bf16(pa, bv.v, pv[nt], 0, 0, 0);
        }
    }
    __builtin_amdgcn_s_setprio(0);

    float invv[4];
#pragma unroll
    for (int r = 0; r < 4; ++r) invv[r] = __shfl(inv, g * 4 + r);
#pragma unroll
    for (int nt = 0; nt < 4; ++nt)
#pragma unroll
        for (int r = 0; r < 4; ++r)
            ctx[((size_t)t * 512 + 32 * (g * 4 + r) + bb) * 64 + nt * 16 + l15] =
                f2bf(pv[nt][r] * invv[r]);
}

// ------------------------------------------------------------------ launch ----
extern "C" void kernel_launch(void* const* d_in, const int* in_sizes, int n_in,
                              void* d_out, int out_size, void* d_ws, size_t ws_size,
                              hipStream_t stream) {
    const float* query = (const float*)d_in[0];
    const float* key   = (const float*)d_in[1];
    const float* value = (const float*)d_in[2];
    const float* Wq = (const float*)d_in[3];  const float* bq = (const float*)d_in[4];
    const float* Wk = (const float*)d_in[5];  const float* bk = (const float*)d_in[6];
    const float* Wv = (const float*)d_in[7];  const float* bv = (const float*)d_in[8];
    const float* Wo = (const float*)d_in[9];  const float* bo = (const float*)d_in[10];

    char* ws = (char*)d_ws;
    // ws (136 MiB): weights bf16 8 | q_ws 32 | k_ws 32 | v_ws 32 | qx 32.
    // d_out `out` region hosts kx/vx during proj GEMM, then vt — dead before
    // gemm_bb<1> writes `out`. ctx aliases q_ws (same-wave read-then-write).
    u16* wqb  = (u16*)(ws + 0);
    u16* wkb  = (u16*)(ws + 2097152);
    u16* wvb  = (u16*)(ws + 4194304);
    u16* wob  = (u16*)(ws + 6291456);
    u16* q_ws = (u16*)(ws + 8388608);
    u16* k_ws = (u16*)(ws + 41943040);
    u16* v_ws = (u16*)(ws + 75497472);
    u16* qx   = (u16*)(ws + 109051904);

    float* out  = (float*)d_out;
    float* wout = out + 16777216;
    u16* kx = (u16*)d_out;                       // 32 MiB scratch in out region
    u16* vx = (u16*)((char*)d_out + 33554432);   // next 32 MiB
    u16* vt = (u16*)((char*)d_out + 33554432);   // reuses vx (dead after proj GEMM)

    convw_kernel<<<2048, 256, 0, stream>>>(
        (const float4*)query, (const float4*)key, (const float4*)value,
        (const float4*)Wq, (const float4*)Wk, (const float4*)Wv, (const float4*)Wo,
        (uint2*)qx, (uint2*)kx, (uint2*)vx,
        (uint2*)wqb, (uint2*)wkb, (uint2*)wvb, (uint2*)wob);

    dim3 gg3(1024, 1, 3);
    gemm_bb<0><<<gg3, 256, 0, stream>>>(qx, kx, vx, wqb, wkb, wvb,
                                        bq, bk, bv, KSC, 1.f, 1.f,
                                        q_ws, k_ws, v_ws);

    vtrans_kernel<<<2048, 256, 0, stream>>>(v_ws, vt);

    attn_kernel<<<2048, 512, 0, stream>>>(q_ws, k_ws, vt, q_ws, wout);

    gemm_bb<1><<<dim3(1024, 1, 1), 256, 0, stream>>>(q_ws, q_ws, q_ws,
                                                     wob, wob, wob, bo, bo, bo,
                                                     1.f, 1.f, 1.f,
                                                     out, out, out);
}

// Round 24
// 304.570 us; speedup vs baseline: 1.0402x; 1.0402x over previous
//
#include <hip/hip_runtime.h>
#include <hip/hip_bf16.h>
#include <stdint.h>

// MultiheadAttention (T=512, B=32, H=16, hd=64, D=1024); bmm batched over seq dim.
// R23 base (best: 315.4us) + one attributable change: attn exp via raw
// __builtin_amdgcn_exp2f (bare v_exp_f32) instead of exp2f's OCML call with
// denorm/range fixups (~4-6 VALU inst x 128 calls in the VALU-issue-bound kernel).
// Domain safe: |zz| <~ 30 after ksc fold -> no denorm/clamp handling needed.

typedef __attribute__((ext_vector_type(8))) short bf16x8;
typedef __attribute__((ext_vector_type(4))) float f32x4;
typedef unsigned short u16;
typedef unsigned int u32;

typedef __attribute__((address_space(1))) const unsigned int as1_u32;
typedef __attribute__((address_space(3))) unsigned int as3_u32;

#define KSC 0.18033688011112042f   // log2(e)/sqrt(64)

__device__ __forceinline__ void glds16(const void* g, void* l) {
    __builtin_amdgcn_global_load_lds((as1_u32*)g, (as3_u32*)l, 16, 0, 0);
}

__device__ __forceinline__ u16 f2bf(float f) {
    u32 u = __builtin_bit_cast(u32, f);
    u32 r = (u + 0x7FFFu + ((u >> 16) & 1u)) >> 16;
    return (u16)r;
}

// HW packed fp32->bf16 RNE: lo(bf16 of a) | hi(bf16 of b). One VALU inst.
__device__ __forceinline__ u32 cvtpk(float a, float b) {
    u32 r;
    asm("v_cvt_pk_bf16_f32 %0, %1, %2" : "=v"(r) : "v"(a), "v"(b));
    return r;
}

// 16-lane-group allreduce, fused DPP adds (src0 routed through DPP network).
__device__ __forceinline__ float red16(float v) {
    float t;
    asm("v_add_f32_dpp %0, %1, %1 quad_perm:[1,0,3,2] row_mask:0xf bank_mask:0xf"
        : "=v"(t) : "v"(v));
    asm("v_add_f32_dpp %0, %1, %1 quad_perm:[2,3,0,1] row_mask:0xf bank_mask:0xf"
        : "=v"(v) : "v"(t));
    asm("v_add_f32_dpp %0, %1, %1 row_half_mirror row_mask:0xf bank_mask:0xf"
        : "=v"(t) : "v"(v));
    asm("v_add_f32_dpp %0, %1, %1 row_mirror row_mask:0xf bank_mask:0xf"
        : "=v"(v) : "v"(t));
    return v;
}

// ---------------- query (remap) + key + value + weights fp32 -> bf16 ----
// Wq is pre-scaled by KSC (bias scaled at gemm epilogue).
__global__ void convw_kernel(const float4* __restrict__ query,
                             const float4* __restrict__ key,
                             const float4* __restrict__ value,
                             const float4* __restrict__ Wq, const float4* __restrict__ Wk,
                             const float4* __restrict__ Wv, const float4* __restrict__ Wo,
                             uint2* __restrict__ qx, uint2* __restrict__ kx,
                             uint2* __restrict__ vx,
                             uint2* __restrict__ wqb, uint2* __restrict__ wkb,
                             uint2* __restrict__ wvb, uint2* __restrict__ wob) {
    const int NT = gridDim.x * blockDim.x;
    for (int i = blockIdx.x * blockDim.x + threadIdx.x; i < 13631488; i += NT) {
        float4 v; uint2* d; int di;
        if (i < 4194304) {
            int m = i >> 8, c4 = i & 255;          // qx row m = t*32 + b
            int t = m >> 5, b = m & 31;
            v = query[(b * 512 + t) * 256 + c4];
            d = qx; di = i;
        } else if (i < 8388608) {
            di = i - 4194304; v = key[di]; d = kx;
        } else if (i < 12582912) {
            di = i - 8388608; v = value[di]; d = vx;
        } else {
            int jj = i - 12582912;
            int wsel = jj >> 18; di = jj & 262143;
            const float4* s = wsel == 0 ? Wq : wsel == 1 ? Wk : wsel == 2 ? Wv : Wo;
            d = wsel == 0 ? wqb : wsel == 1 ? wkb : wsel == 2 ? wvb : wob;
            v = s[di];
            if (wsel == 0) { v.x *= KSC; v.y *= KSC; v.z *= KSC; v.w *= KSC; }
        }
        uint2 r;
        r.x = (u32)f2bf(v.x) | ((u32)f2bf(v.y) << 16);
        r.y = (u32)f2bf(v.z) | ((u32)f2bf(v.w) << 16);
        d[di] = r;
    }
}

// ---------------------------------------------------------- bf16 GEMM ----
// Single-buffered m97 structure: {glds(kt); bar; 32 MFMA; bar}. 32KB LDS, (256,4).
template <int F32OUT>
__global__ __launch_bounds__(256, 4)
void gemm_bb(const u16* __restrict__ A0, const u16* __restrict__ A1,
             const u16* __restrict__ A2,
             const u16* __restrict__ B0, const u16* __restrict__ B1,
             const u16* __restrict__ B2,
             const float* __restrict__ b0, const float* __restrict__ b1,
             const float* __restrict__ b2,
             float s0, float s1, float s2,
             void* __restrict__ C0, void* __restrict__ C1, void* __restrict__ C2) {
    __shared__ __align__(16) u16 As[8192];
    __shared__ __align__(16) u16 Bs[8192];
    const int z = blockIdx.z;
    const u16* A = z == 0 ? A0 : z == 1 ? A1 : A2;
    const u16* B = z == 0 ? B0 : z == 1 ? B1 : B2;
    const float* bias = z == 0 ? b0 : z == 1 ? b1 : b2;
    const float bsc = z == 0 ? s0 : z == 1 ? s1 : s2;
    void* Cp = z == 0 ? C0 : z == 1 ? C1 : C2;
    const int tid = threadIdx.x;
    const int id = blockIdx.x;
    const int xcd = id & 7, j = id >> 3;
    const int ny = j & 7, band = xcd * 16 + (j >> 3);
    const long N0 = (long)ny * 128;
    const long M0 = (long)band * 128;
    const int lane = tid & 63, wv = tid >> 6;
    const int l15 = lane & 15, g = lane >> 4;
    const int wm = (wv >> 1) * 64, wn = (wv & 1) * 64;

    auto gldsAB = [&](int kt) {
#pragma unroll
        for (int i2 = 0; i2 < 4; ++i2) {
            int q = tid + 256 * i2; int r = q >> 3, c16 = q & 7;
            int c16s = c16 ^ (r & 7);   // pre-swizzled source: lds stays linear
            char* lbA = (char*)As + (i2 * 256 + wv * 64) * 16;
            char* lbB = (char*)Bs + (i2 * 256 + wv * 64) * 16;
            glds16(A + (M0 + r) * 1024 + kt * 64 + c16s * 8, lbA);
            glds16(B + (N0 + r) * 1024 + kt * 64 + c16s * 8, lbB);
        }
    };
    f32x4 acc[4][4] = {};
    const int swz = (l15 & 7) << 4;
    for (int kt = 0; kt < 16; ++kt) {
        gldsAB(kt);
        __syncthreads();   // glds drained: tile kt resident
#pragma unroll
        for (int kk = 0; kk < 2; ++kk) {
            bf16x8 av[4], bvv[4];
#pragma unroll
            for (int mt = 0; mt < 4; ++mt) {
                int row = wm + mt * 16 + l15;
                av[mt] = *(const bf16x8*)((const char*)As + row * 128 + ((kk * 64 + g * 16) ^ swz));
            }
#pragma unroll
            for (int nt = 0; nt < 4; ++nt) {
                int row = wn + nt * 16 + l15;
                bvv[nt] = *(const bf16x8*)((const char*)Bs + row * 128 + ((kk * 64 + g * 16) ^ swz));
            }
#pragma unroll
            for (int mt = 0; mt < 4; ++mt)
#pragma unroll
                for (int nt = 0; nt < 4; ++nt)
                    acc[mt][nt] = __builtin_amdgcn_mfma_f32_16x16x32_bf16(av[mt], bvv[nt], acc[mt][nt], 0, 0, 0);
        }
        __syncthreads();   // all reads done before next tile's glds
    }
    float bsv[4];
#pragma unroll
    for (int nt = 0; nt < 4; ++nt) bsv[nt] = bias[N0 + wn + nt * 16 + l15] * bsc;
#pragma unroll
    for (int mt = 0; mt < 4; ++mt)
#pragma unroll
        for (int nt = 0; nt < 4; ++nt)
#pragma unroll
            for (int r = 0; r < 4; ++r) {
                long m = M0 + wm + mt * 16 + g * 4 + r;
                long n = N0 + wn + nt * 16 + l15;
                float v = acc[mt][nt][r] + bsv[nt];
                if (F32OUT) ((float*)Cp)[m * 1024 + n] = v;
                else        ((u16*)Cp)[m * 1024 + n] = f2bf(v);
            }
}

// ------------------------------------------------- V transpose: [t][c][e] -> [t][e][c]
__global__ __launch_bounds__(256)
void vtrans_kernel(const u16* __restrict__ v_ws, u16* __restrict__ vt) {
    __shared__ __align__(16) u16 tl[64][136];
    const int bid = blockIdx.x;
    const int t = bid >> 2, c0 = (bid & 3) * 128;
    const u16* src = v_ws + (size_t)t * 32768 + (size_t)c0 * 64;
#pragma unroll
    for (int i = 0; i < 4; ++i) {
        int ch = i * 256 + threadIdx.x;
        int rc = ch >> 3, e0 = (ch & 7) * 8;
        bf16x8 v8 = *(const bf16x8*)(src + rc * 64 + e0);
#pragma unroll
        for (int j = 0; j < 8; ++j) tl[e0 + j][rc] = (u16)v8[j];
    }
    __syncthreads();
    u16* dst = vt + (size_t)t * 32768 + c0;
#pragma unroll
    for (int i = 0; i < 4; ++i) {
        int ch = i * 256 + threadIdx.x;
        int e = ch >> 4, cc = (ch & 15) * 8;
        *(bf16x8*)(dst + (size_t)e * 512 + cc) = *(const bf16x8*)(&tl[e][cc]);
    }
}

// ------------------------------------------------------------- fused attn ----
// Grid 2048: block = (t, it); 8 waves; wave owns bb = it*8+wv; cols c = 32*l15+bb.
// 3 barriers: {stage all K; BAR; all QK^T+exp2+cvt_pk; BAR; stage all V^T +
// w-phase (fused-DPP reduce); BAR; all PV; epilogue}. Q pre-scaled by KSC.
__global__ __launch_bounds__(512, 2)
void attn_kernel(const u16* __restrict__ Q, const u16* __restrict__ K,
                 const u16* __restrict__ VT, u16* __restrict__ ctx,
                 float* __restrict__ wout) {
    __shared__ __align__(16) char smem[65536];
    const int bid = blockIdx.x;
    const int wk_ = (bid & 7) * 256 + (bid >> 3);   // bijective (2048 % 8 == 0)
    const int t = wk_ >> 2, it = wk_ & 3;
    const int tid = threadIdx.x, lane = tid & 63, wv = tid >> 6;
    const int l15 = lane & 15, g = lane >> 4;
    const int swk = (l15 & 7) << 4;
    const int bb = it * 8 + wv;

    const u16* Kt = K + (size_t)t * 32768;
    const u16* Vtt = VT + (size_t)t * 32768;   // [e][c] rows of 512

    // ---- stage ALL of K (64KB): [512 s][128B], 16B-chunk swizzle c16^(sl&7) ----
    {
#pragma unroll
        for (int hh = 0; hh < 8; ++hh) {
            int idx = hh * 512 + tid;
            int sl = idx >> 3, c16 = idx & 7;
            int csw = c16 ^ (sl & 7);
            glds16(Kt + (size_t)sl * 64 + csw * 8, smem + hh * 8192 + wv * 1024);
        }
    }
    const int c = 32 * l15 + bb;
    const u16* qrow = Q + ((size_t)t * 512 + c) * 64;
    bf16x8 qb0 = *(const bf16x8*)(qrow + g * 8);
    bf16x8 qb1 = *(const bf16x8*)(qrow + 32 + g * 8);
    __syncthreads();   // BAR 1: K resident

    // ---- all QK^T + raw v_exp_f32 + cvt_pk, barrier-free ----
    float sum = 0.f;
    bf16x8 pP[16];
    __builtin_amdgcn_s_setprio(1);
#pragma unroll
    for (int mq = 0; mq < 16; ++mq) {
        union { bf16x8 v; u32 u[4]; } pa;
#pragma unroll
        for (int h2 = 0; h2 < 2; ++h2) {
            int lsl = 2 * mq + h2;   // 0..31, s = lsl*16 + 4g + r
            const char* rowp = smem + (lsl * 16 + l15) * 128;
            bf16x8 a0 = *(const bf16x8*)(rowp + ((g * 16) ^ swk));
            bf16x8 a1 = *(const bf16x8*)(rowp + ((64 + g * 16) ^ swk));
            f32x4 zz = {0.f, 0.f, 0.f, 0.f};
            zz = __builtin_amdgcn_mfma_f32_16x16x32_bf16(a0, qb0, zz, 0, 0, 0);
            zz = __builtin_amdgcn_mfma_f32_16x16x32_bf16(a1, qb1, zz, 0, 0, 0);
            float e0 = __builtin_amdgcn_exp2f(zz[0]);
            float e1 = __builtin_amdgcn_exp2f(zz[1]);
            float e2 = __builtin_amdgcn_exp2f(zz[2]);
            float e3 = __builtin_amdgcn_exp2f(zz[3]);
            sum += (e0 + e1) + (e2 + e3);
            pa.u[2 * h2]     = cvtpk(e0, e1);
            pa.u[2 * h2 + 1] = cvtpk(e2, e3);
        }
        pP[mq] = pa.v;
    }
    __builtin_amdgcn_s_setprio(0);
    sum += __shfl_xor(sum, 16);
    sum += __shfl_xor(sum, 32);
    const float inv = 1.f / sum;
    __syncthreads();   // BAR 2: all waves done reading K

    // ---- stage ALL of V^T (64KB, overwrites K): rows e = 1024B, chunk c6^(e&7) ----
    {
#pragma unroll
        for (int hh = 0; hh < 8; ++hh) {
            int ch = hh * 512 + tid;
            int e = ch >> 6, c6 = ch & 63;
            int csw = c6 ^ (e & 7);
            glds16(Vtt + (size_t)e * 512 + csw * 8, smem + hh * 8192 + wv * 1024);
        }
    }
    // ---- w head-mean (fused-DPP allreduce over l15) — V transfer underneath ----
    {
        const float inv16 = inv * 0.0625f;
        float4 wreg0 = {0.f, 0.f, 0.f, 0.f}, wreg1 = {0.f, 0.f, 0.f, 0.f};
#pragma unroll
        for (int st = 0; st < 32; ++st) {
            union { bf16x8 v; u32 u[4]; } pu; pu.v = pP[st >> 1];
            u32 ua = pu.u[(st & 1) * 2], ub = pu.u[(st & 1) * 2 + 1];
            float v0 = __builtin_bit_cast(float, ua << 16) * inv16;
            float v1 = __builtin_bit_cast(float, ua & 0xFFFF0000u) * inv16;
            float v2 = __builtin_bit_cast(float, ub << 16) * inv16;
            float v3 = __builtin_bit_cast(float, ub & 0xFFFF0000u) * inv16;
            v0 = red16(v0); v1 = red16(v1); v2 = red16(v2); v3 = red16(v3);
            if ((st >> 1) == l15) {
                if (st & 1) wreg1 = (float4){v0, v1, v2, v3};
                else        wreg0 = (float4){v0, v1, v2, v3};
            }
        }
        float* wrow = wout + ((size_t)(bb * 512 + t)) * 512 + 32 * l15 + 4 * g;
        *(float4*)(wrow) = wreg0;
        *(float4*)(wrow + 16) = wreg1;
    }
    __syncthreads();   // BAR 3: V^T resident

    // ---- all PV, barrier-free ----
    f32x4 pv[4];
#pragma unroll
    for (int nt = 0; nt < 4; ++nt) pv[nt] = (f32x4){0.f, 0.f, 0.f, 0.f};
    __builtin_amdgcn_s_setprio(1);
#pragma unroll
    for (int mq = 0; mq < 16; ++mq) {
        bf16x8 pa = pP[mq];
#pragma unroll
        for (int nt = 0; nt < 4; ++nt) {
            int e = nt * 16 + l15;
            const char* vrow = smem + e * 1024;
            int off = mq * 64 + 8 * g;
            union { bf16x8 v; uint2 uu[2]; } bv;
            bv.uu[0] = *(const uint2*)(vrow + (off ^ swk));
            bv.uu[1] = *(const uint2*)(vrow + ((off + 32) ^ swk));
            pv[nt] = __builtin_amdgcn_mfma_f32_16x16x32_bf16(pa, bv.v, pv[nt], 0, 0, 0);
        }
    }
    __builtin_amdgcn_s_setprio(0);

    float invv[4];
#pragma unroll
    for (int r = 0; r < 4; ++r) invv[r] = __shfl(inv, g * 4 + r);
#pragma unroll
    for (int nt = 0; nt < 4; ++nt)
#pragma unroll
        for (int r = 0; r < 4; ++r)
            ctx[((size_t)t * 512 + 32 * (g * 4 + r) + bb) * 64 + nt * 16 + l15] =
                f2bf(pv[nt][r] * invv[r]);
}

// ------------------------------------------------------------------ launch ----
extern "C" void kernel_launch(void* const* d_in, const int* in_sizes, int n_in,
                              void* d_out, int out_size, void* d_ws, size_t ws_size,
                              hipStream_t stream) {
    const float* query = (const float*)d_in[0];
    const float* key   = (const float*)d_in[1];
    const float* value = (const float*)d_in[2];
    const float* Wq = (const float*)d_in[3];  const float* bq = (const float*)d_in[4];
    const float* Wk = (const float*)d_in[5];  const float* bk = (const float*)d_in[6];
    const float* Wv = (const float*)d_in[7];  const float* bv = (const float*)d_in[8];
    const float* Wo = (const float*)d_in[9];  const float* bo = (const float*)d_in[10];

    char* ws = (char*)d_ws;
    // ws (136 MiB): weights bf16 8 | q_ws 32 | k_ws 32 | v_ws 32 | qx 32.
    // d_out `out` region hosts kx/vx during proj GEMM, then vt — dead before
    // gemm_bb<1> writes `out`. ctx aliases q_ws (same-wave read-then-write).
    u16* wqb  = (u16*)(ws + 0);
    u16* wkb  = (u16*)(ws + 2097152);
    u16* wvb  = (u16*)(ws + 4194304);
    u16* wob  = (u16*)(ws + 6291456);
    u16* q_ws = (u16*)(ws + 8388608);
    u16* k_ws = (u16*)(ws + 41943040);
    u16* v_ws = (u16*)(ws + 75497472);
    u16* qx   = (u16*)(ws + 109051904);

    float* out  = (float*)d_out;
    float* wout = out + 16777216;
    u16* kx = (u16*)d_out;                       // 32 MiB scratch in out region
    u16* vx = (u16*)((char*)d_out + 33554432);   // next 32 MiB
    u16* vt = (u16*)((char*)d_out + 33554432);   // reuses vx (dead after proj GEMM)

    convw_kernel<<<2048, 256, 0, stream>>>(
        (const float4*)query, (const float4*)key, (const float4*)value,
        (const float4*)Wq, (const float4*)Wk, (const float4*)Wv, (const float4*)Wo,
        (uint2*)qx, (uint2*)kx, (uint2*)vx,
        (uint2*)wqb, (uint2*)wkb, (uint2*)wvb, (uint2*)wob);

    dim3 gg3(1024, 1, 3);
    gemm_bb<0><<<gg3, 256, 0, stream>>>(qx, kx, vx, wqb, wkb, wvb,
                                        bq, bk, bv, KSC, 1.f, 1.f,
                                        q_ws, k_ws, v_ws);

    vtrans_kernel<<<2048, 256, 0, stream>>>(v_ws, vt);

    attn_kernel<<<2048, 512, 0, stream>>>(q_ws, k_ws, vt, q_ws, wout);

    gemm_bb<1><<<dim3(1024, 1, 1), 256, 0, stream>>>(q_ws, q_ws, q_ws,
                                                     wob, wob, wob, bo, bo, bo,
                                                     1.f, 1.f, 1.f,
                                                     out, out, out);
}